// Round 11
// baseline (131.805 us; speedup 1.0000x reference)
//
#include <hip/hip_runtime.h>
#include <stdint.h>

typedef _Float16  f16;
typedef f16       f16x2  __attribute__((ext_vector_type(2)));
typedef f16       f16x8  __attribute__((ext_vector_type(8)));
typedef float     f32x16v __attribute__((ext_vector_type(16)));
typedef float     f32x4v  __attribute__((ext_vector_type(4)));
typedef uint32_t  u32x4v  __attribute__((ext_vector_type(4)));
typedef unsigned short u16;

__device__ __forceinline__ f32x16v mfma16h(u32x4v a, u32x4v b, f32x16v c) {
  return __builtin_amdgcn_mfma_f32_32x32x16_f16(
      __builtin_bit_cast(f16x8, a), __builtin_bit_cast(f16x8, b), c, 0, 0, 0);
}

// prep: W f32 [65][i=64][k=64] -> fragment-major f16 arrays (B-operand form).
// elem idx = jj*4096 + (ct*4+s)*512 + l*8 + e  (l = lane)
//   w1h: W[jj][ i=s*16+(l>>5)*8+e ][ k=ct*32+(l&31) ]
//   w2h: W[jj][ e_row=ct*32+(l&31) ][ k=s*16+(l>>5)*8+e ]
__global__ __launch_bounds__(256) void prep_w(const float* __restrict__ W,
                                              u16* __restrict__ w1h,
                                              u16* __restrict__ w2h) {
  __shared__ float Wl[4096];
  const int jj = blockIdx.x;
  const int t  = threadIdx.x;
  for (int idx = t; idx < 4096; idx += 256) Wl[idx] = W[jj * 4096 + idx];
  __syncthreads();
  for (int pq = t; pq < 512; pq += 256) {
    const int c2 = pq >> 6, l = pq & 63;
    const int ct = c2 >> 2, s = c2 & 3;
    const int rowA = ct * 32 + (l & 31);
    const int k0   = s * 16 + (l >> 5) * 8;
    u16 v1[8], v2[8];
    #pragma unroll
    for (int e = 0; e < 8; ++e) {
      v2[e] = __builtin_bit_cast(u16, (f16)Wl[rowA * 64 + k0 + e]);
      v1[e] = __builtin_bit_cast(u16, (f16)Wl[(k0 + e) * 64 + rowA]);
    }
    u32x4v pk1, pk2;
    #pragma unroll
    for (int q = 0; q < 4; ++q) {
      pk1[q] = (uint32_t)v1[2*q] | ((uint32_t)v1[2*q+1] << 16);
      pk2[q] = (uint32_t)v2[2*q] | ((uint32_t)v2[2*q+1] << 16);
    }
    *reinterpret_cast<u32x4v*>(w1h + jj * 4096 + pq * 8) = pk1;
    *reinterpret_cast<u32x4v*>(w2h + jj * 4096 + pq * 8) = pk2;
  }
}

// main: grid 256 (1 block/CU), 512 thr (8 waves), BB=128.
// wave role = (ct, sq): owns ONE 1KB B-fragment per j (its output-col half x
// its K-quarter), for ALL 4 sample-tiles. Wave-private 3-slot staging ring,
// counted vmcnt, ZERO barriers in the K-loop. K-partials combined across the
// 4 sq-waves per ct via LDS atomicAdd once per pass.
__global__ __launch_bounds__(512, 2) void rquad_main(
    const float* __restrict__ x, const float* __restrict__ g,
    const u16* __restrict__ w1h, const u16* __restrict__ w2h,
    float* __restrict__ out) {
  __shared__ u16      stage[3 * 16384];   // 3 slots x 32KB (4j x 8 frags x 1KB)
  __shared__ float    vl[128 * 68];       // 34.8 KB combine buffer [b][k]
  __shared__ uint32_t x1p[65 * 64];       // 16.6 KB packed x1 f16-pairs

  const int t    = threadIdx.x;
  const int lane = t & 63;
  const int wv   = t >> 6;
  const int ct   = wv >> 2;         // output-col half (k / e)
  const int sq   = wv & 3;          // K-quarter (i for pass1, k for pass2)
  const int bl   = lane & 31;
  const int half = lane >> 5;
  const long base = (long)blockIdx.x * 128;

  // x -> vl (coalesced), then pack x1p[j][q] = (f16 x[q][j], f16 x[64+q][j])
  for (int q = t; q < 2048; q += 512) {
    const int row = q >> 4, c4 = (q & 15) * 4;
    *reinterpret_cast<f32x4v*>(&vl[row * 68 + c4]) =
        *reinterpret_cast<const f32x4v*>(&x[(base + row) * 64 + c4]);
  }
  __syncthreads();
  for (int idx = t; idx < 65 * 64; idx += 512) {
    const int j = idx >> 6, q = idx & 63;
    uint32_t val;
    if (j == 64) val = 0x3C003C00u;                 // bias 1.0,1.0
    else {
      f16 a = (f16)vl[q * 68 + j];
      f16 b = (f16)vl[(64 + q) * 68 + j];
      val = (uint32_t)__builtin_bit_cast(u16, a) |
            ((uint32_t)__builtin_bit_cast(u16, b) << 16);
    }
    x1p[idx] = val;
  }
  // z init from g: K-slice i = sq*16 + half*8 + 0..7, per tile
  f16x2 z[4][4];
  #pragma unroll
  for (int tt = 0; tt < 4; ++tt) {
    const float* gp = g + (base + tt * 32 + bl) * 64 + sq * 16 + half * 8;
    f32x4v a = *reinterpret_cast<const f32x4v*>(gp);
    f32x4v b = *reinterpret_cast<const f32x4v*>(gp + 4);
    z[tt][0] = f16x2{(f16)a[0], (f16)a[1]};
    z[tt][1] = f16x2{(f16)a[2], (f16)a[3]};
    z[tt][2] = f16x2{(f16)b[0], (f16)b[1]};
    z[tt][3] = f16x2{(f16)b[2], (f16)b[3]};
  }
  __syncthreads();
  for (int idx = t; idx < 128 * 68; idx += 512) vl[idx] = 0.0f;
  __syncthreads();

  f32x16v acc[4];
  const int fragoff = ct * 2048 + sq * 512;   // u16 elems within a j-slot

  auto stage_chunk = [&](const u16* __restrict__ Wsrc, int c) {
    if (c > 16) return;
    const int nu = (c == 16) ? 1 : 4;
    u16* dstb = &stage[(c % 3) * 16384 + fragoff];          // wave-uniform base
    const u16* srcb = Wsrc + (size_t)c * 4 * 4096 + fragoff + lane * 8;
    for (int u = 0; u < nu; ++u)
      __builtin_amdgcn_global_load_lds(
          (const __attribute__((address_space(1))) void*)(srcb + (size_t)u * 4096),
          (__attribute__((address_space(3))) void*)(dstb + u * 4096),
          16, 0, 0);
  };

  auto compute_chunk = [&](int st) {
    const int nj = (st == 16) ? 1 : 4;
    const u16* sb = &stage[(st % 3) * 16384 + fragoff + lane * 8];
    for (int jl = 0; jl < nj; ++jl) {
      const int jglob = st * 4 + jl;
      u32x4v B = *reinterpret_cast<const u32x4v*>(sb + jl * 4096);
      const uint32_t xw0 = x1p[jglob * 64 + bl];        // tiles 0(lo), 2(hi)
      const uint32_t xw1 = x1p[jglob * 64 + 32 + bl];   // tiles 1(lo), 3(hi)
      const f16x2 xp0 = __builtin_bit_cast(f16x2, xw0);
      const f16x2 xp1 = __builtin_bit_cast(f16x2, xw1);
      const f16x2 xb0 = f16x2{xp0[0], xp0[0]};
      const f16x2 xb1 = f16x2{xp1[0], xp1[0]};
      const f16x2 xb2 = f16x2{xp0[1], xp0[1]};
      const f16x2 xb3 = f16x2{xp1[1], xp1[1]};
      u32x4v a0, a1, a2, a3;
      #pragma unroll
      for (int q = 0; q < 4; ++q) {
        a0[q] = __builtin_bit_cast(uint32_t, f16x2(xb0 * z[0][q]));
        a1[q] = __builtin_bit_cast(uint32_t, f16x2(xb1 * z[1][q]));
        a2[q] = __builtin_bit_cast(uint32_t, f16x2(xb2 * z[2][q]));
        a3[q] = __builtin_bit_cast(uint32_t, f16x2(xb3 * z[3][q]));
      }
      acc[0] = mfma16h(a0, B, acc[0]);
      acc[1] = mfma16h(a1, B, acc[1]);
      acc[2] = mfma16h(a2, B, acc[2]);
      acc[3] = mfma16h(a3, B, acc[3]);
    }
  };

  auto run_pass = [&](const u16* __restrict__ Wsrc) {
    #pragma unroll
    for (int tt = 0; tt < 4; ++tt)
      #pragma unroll
      for (int r = 0; r < 16; ++r) acc[tt][r] = 0.0f;
    stage_chunk(Wsrc, 0);
    stage_chunk(Wsrc, 1);
    stage_chunk(Wsrc, 2);
    for (int st = 0; st <= 16; ++st) {
      // wait own oldest chunk landed; keep st+1, st+2 in flight
      if (st < 14)       asm volatile("s_waitcnt vmcnt(8)" ::: "memory");
      else if (st == 14) asm volatile("s_waitcnt vmcnt(5)" ::: "memory");
      else if (st == 15) asm volatile("s_waitcnt vmcnt(1)" ::: "memory");
      else               asm volatile("s_waitcnt vmcnt(0)" ::: "memory");
      __builtin_amdgcn_sched_barrier(0);
      compute_chunk(st);
      __builtin_amdgcn_sched_barrier(0);
      stage_chunk(Wsrc, st + 3);    // overwrites slot st%3 (already consumed)
    }
  };

  // ---------------- pass 1: v[b,k] ----------------
  run_pass(w1h);
  #pragma unroll
  for (int tt = 0; tt < 4; ++tt)
    #pragma unroll
    for (int r = 0; r < 16; ++r) {
      const int rr = (r & 3) + 8 * (r >> 2) + 4 * half;
      atomicAdd(&vl[(tt * 32 + rr) * 68 + ct * 32 + bl], acc[tt][r]);
    }
  __syncthreads();
  // z <- v (f32 -> f16), K-slice k = sq*16 + half*8 + 0..7
  #pragma unroll
  for (int tt = 0; tt < 4; ++tt) {
    const float* vp = &vl[(tt * 32 + bl) * 68 + sq * 16 + half * 8];
    f32x4v a = *reinterpret_cast<const f32x4v*>(vp);
    f32x4v b = *reinterpret_cast<const f32x4v*>(vp + 4);
    z[tt][0] = f16x2{(f16)a[0], (f16)a[1]};
    z[tt][1] = f16x2{(f16)a[2], (f16)a[3]};
    z[tt][2] = f16x2{(f16)b[0], (f16)b[1]};
    z[tt][3] = f16x2{(f16)b[2], (f16)b[3]};
  }
  __syncthreads();
  for (int idx = t; idx < 128 * 68; idx += 512) vl[idx] = 0.0f;
  __syncthreads();

  // ---------------- pass 2: out[b,e] ----------------
  run_pass(w2h);
  #pragma unroll
  for (int tt = 0; tt < 4; ++tt)
    #pragma unroll
    for (int r = 0; r < 16; ++r) {
      const int rr = (r & 3) + 8 * (r >> 2) + 4 * half;
      atomicAdd(&vl[(tt * 32 + rr) * 68 + ct * 32 + bl], acc[tt][r]);
    }
  __syncthreads();
  for (int q = t; q < 2048; q += 512) {
    const int row = q >> 4, c4 = (q & 15) * 4;
    f32x4v v4 = *reinterpret_cast<const f32x4v*>(&vl[row * 68 + c4]);
    f32x4v o;
    o[0] = v4[0] * 0.125f; o[1] = v4[1] * 0.125f;
    o[2] = v4[2] * 0.125f; o[3] = v4[3] * 0.125f;
    *reinterpret_cast<f32x4v*>(&out[(base + row) * 64 + c4]) = o;
  }
}

extern "C" void kernel_launch(void* const* d_in, const int* in_sizes, int n_in,
                              void* d_out, int out_size, void* d_ws, size_t ws_size,
                              hipStream_t stream) {
  const float* x = (const float*)d_in[0];
  const float* g = (const float*)d_in[1];
  const float* W = (const float*)d_in[2];
  float* o = (float*)d_out;
  u16* w1h = (u16*)d_ws;                    // 65*4096 f16 = 520 KiB
  u16* w2h = w1h + 65 * 4096;               // another 520 KiB
  hipLaunchKernelGGL(prep_w, dim3(65), dim3(256), 0, stream, W, w1h, w2h);
  hipLaunchKernelGGL(rquad_main, dim3(256), dim3(512), 0, stream, x, g, w1h, w2h, o);
}

// Round 12
// 61.634 us; speedup vs baseline: 2.1385x; 2.1385x over previous
//
#include <hip/hip_runtime.h>
#include <stdint.h>

typedef _Float16  f16;
typedef f16       f16x2  __attribute__((ext_vector_type(2)));
typedef f16       f16x8  __attribute__((ext_vector_type(8)));
typedef float     f32x16v __attribute__((ext_vector_type(16)));
typedef float     f32x4v  __attribute__((ext_vector_type(4)));
typedef uint32_t  u32x4v  __attribute__((ext_vector_type(4)));
typedef unsigned short u16;

__device__ __forceinline__ f32x16v mfma16h(u32x4v a, u32x4v b, f32x16v c) {
  return __builtin_amdgcn_mfma_f32_32x32x16_f16(
      __builtin_bit_cast(f16x8, a), __builtin_bit_cast(f16x8, b), c, 0, 0, 0);
}

// prep: W f32 [65][i=64][k=64] -> fragment-major f16 arrays (B-operand form).
// elem idx = jj*4096 + (ct*4+s)*512 + l*8 + e  (l = lane)
//   w1h: W[jj][ i=s*16+(l>>5)*8+e ][ k=ct*32+(l&31) ]
//   w2h: W[jj][ e_row=ct*32+(l&31) ][ k=s*16+(l>>5)*8+e ]
__global__ __launch_bounds__(256) void prep_w(const float* __restrict__ W,
                                              u16* __restrict__ w1h,
                                              u16* __restrict__ w2h) {
  __shared__ float Wl[4096];
  const int jj = blockIdx.x;
  const int t  = threadIdx.x;
  for (int idx = t; idx < 4096; idx += 256) Wl[idx] = W[jj * 4096 + idx];
  __syncthreads();
  for (int pq = t; pq < 512; pq += 256) {
    const int c2 = pq >> 6, l = pq & 63;
    const int ct = c2 >> 2, s = c2 & 3;
    const int rowA = ct * 32 + (l & 31);
    const int k0   = s * 16 + (l >> 5) * 8;
    u16 v1[8], v2[8];
    #pragma unroll
    for (int e = 0; e < 8; ++e) {
      v2[e] = __builtin_bit_cast(u16, (f16)Wl[rowA * 64 + k0 + e]);
      v1[e] = __builtin_bit_cast(u16, (f16)Wl[(k0 + e) * 64 + rowA]);
    }
    u32x4v pk1, pk2;
    #pragma unroll
    for (int q = 0; q < 4; ++q) {
      pk1[q] = (uint32_t)v1[2*q] | ((uint32_t)v1[2*q+1] << 16);
      pk2[q] = (uint32_t)v2[2*q] | ((uint32_t)v2[2*q+1] << 16);
    }
    *reinterpret_cast<u32x4v*>(w1h + jj * 4096 + pq * 8) = pk1;
    *reinterpret_cast<u32x4v*>(w2h + jj * 4096 + pq * 8) = pk2;
  }
}

// main: grid 512 x 256 thr (4 waves), 64 samples/block, 2 blocks/CU resident
// (LDS 72KB). Waves = ct2 x sh2; wave computes both 32-sample tiles for its
// (output-col half, K-half). Barrier-per-chunk (4j), compiler-managed waits,
// global_load_lds staging, read-once LDS. Two independent barrier groups/CU.
__global__ __launch_bounds__(256) void rquad_main(
    const float* __restrict__ x, const float* __restrict__ g,
    const u16* __restrict__ w1h, const u16* __restrict__ w2h,
    float* __restrict__ out) {
  __shared__ __align__(16) u16 stage[2][16384];   // 2 x 32 KB (4j x 8 frags x 1KB)
  __shared__ __align__(16) u16 x1u[65 * 64 + 32]; // f16 x1 [j][sample], 8.4 KB

  float* vl = reinterpret_cast<float*>(&stage[0][0]);  // [64][68] overlay, 17.4 KB

  const int t    = threadIdx.x;
  const int lane = t & 63;
  const int wv   = t >> 6;
  const int ct   = wv >> 1;         // output-col half (k / e)
  const int sh   = wv & 1;          // K-half: s in {2sh, 2sh+1}
  const int bl   = lane & 31;
  const int half = lane >> 5;
  const long base = (long)blockIdx.x * 64;

  // prologue: coalesced x -> vl, then pack x1u[j][q] = f16(x[q][j])
  for (int q = t; q < 1024; q += 256) {
    const int row = q >> 4, c4 = (q & 15) * 4;
    *reinterpret_cast<f32x4v*>(&vl[row * 68 + c4]) =
        *reinterpret_cast<const f32x4v*>(&x[(base + row) * 64 + c4]);
  }
  __syncthreads();
  for (int idx = t; idx < 65 * 64; idx += 256) {
    const int j = idx >> 6, q = idx & 63;
    x1u[idx] = (j == 64) ? (u16)0x3C00
                         : __builtin_bit_cast(u16, (f16)vl[q * 68 + j]);
  }
  // z init from g: K-slice s = 2sh+u, elems s*16 + half*8 + 0..7
  f16x2 z0[2][4], z1[2][4];   // [u][pair], tiles 0 / 1
  #pragma unroll
  for (int u = 0; u < 2; ++u) {
    const int s = 2 * sh + u;
    const float* gp0 = g + (base + bl) * 64 + s * 16 + half * 8;
    const float* gp1 = g + (base + 32 + bl) * 64 + s * 16 + half * 8;
    f32x4v a = *reinterpret_cast<const f32x4v*>(gp0);
    f32x4v b = *reinterpret_cast<const f32x4v*>(gp0 + 4);
    f32x4v c = *reinterpret_cast<const f32x4v*>(gp1);
    f32x4v d = *reinterpret_cast<const f32x4v*>(gp1 + 4);
    z0[u][0] = f16x2{(f16)a[0],(f16)a[1]}; z0[u][1] = f16x2{(f16)a[2],(f16)a[3]};
    z0[u][2] = f16x2{(f16)b[0],(f16)b[1]}; z0[u][3] = f16x2{(f16)b[2],(f16)b[3]};
    z1[u][0] = f16x2{(f16)c[0],(f16)c[1]}; z1[u][1] = f16x2{(f16)c[2],(f16)c[3]};
    z1[u][2] = f16x2{(f16)d[0],(f16)d[1]}; z1[u][3] = f16x2{(f16)d[2],(f16)d[3]};
  }
  __syncthreads();  // x1u ready, vl consumed

  f32x16v acc0, acc1;

  auto stage_chunk = [&](const u16* __restrict__ Wsrc, int c, int buf) {
    if (c > 16) return;
    const int nq = (c == 16) ? 8 : 32;     // 1-KB wave loads
    for (int q = wv; q < nq; q += 4) {
      const u16* src = Wsrc + ((size_t)c * 4 + (q >> 3)) * 4096 + (q & 7) * 512 + lane * 8;
      __builtin_amdgcn_global_load_lds(
          (const __attribute__((address_space(1))) void*)src,
          (__attribute__((address_space(3))) void*)(&stage[buf][q * 512]),
          16, 0, 0);
    }
  };

  auto compute_j = [&](int buf, int jl, int jglob) {
    const u16* sb = &stage[buf][(jl * 8 + ct * 4 + sh * 2) * 512 + lane * 8];
    u32x4v B0 = *reinterpret_cast<const u32x4v*>(sb);
    u32x4v B1 = *reinterpret_cast<const u32x4v*>(sb + 512);
    const f16 xh0 = __builtin_bit_cast(f16, x1u[jglob * 64 + bl]);
    const f16 xh1 = __builtin_bit_cast(f16, x1u[jglob * 64 + 32 + bl]);
    const f16x2 xb0 = f16x2{xh0, xh0}, xb1 = f16x2{xh1, xh1};
    u32x4v a00, a01, a10, a11;
    #pragma unroll
    for (int q = 0; q < 4; ++q) {
      a00[q] = __builtin_bit_cast(uint32_t, f16x2(xb0 * z0[0][q]));
      a10[q] = __builtin_bit_cast(uint32_t, f16x2(xb1 * z1[0][q]));
      a01[q] = __builtin_bit_cast(uint32_t, f16x2(xb0 * z0[1][q]));
      a11[q] = __builtin_bit_cast(uint32_t, f16x2(xb1 * z1[1][q]));
    }
    acc0 = mfma16h(a00, B0, acc0);
    acc1 = mfma16h(a10, B0, acc1);
    acc0 = mfma16h(a01, B1, acc0);
    acc1 = mfma16h(a11, B1, acc1);
  };

  auto run_pass = [&](const u16* __restrict__ Wsrc) {
    #pragma unroll
    for (int r = 0; r < 16; ++r) { acc0[r] = 0.0f; acc1[r] = 0.0f; }
    stage_chunk(Wsrc, 0, 0);
    __syncthreads();
    for (int c = 0; c <= 16; ++c) {
      stage_chunk(Wsrc, c + 1, (c + 1) & 1);
      const int nj = (c == 16) ? 1 : 4;
      for (int jl = 0; jl < nj; ++jl) compute_j(c & 1, jl, c * 4 + jl);
      __syncthreads();
    }
  };

  auto combine = [&]() {
    if (sh == 0) {
      #pragma unroll
      for (int r = 0; r < 16; ++r) {
        const int rr = (r & 3) + 8 * (r >> 2) + 4 * half;
        vl[rr * 68 + ct * 32 + bl]        = acc0[r];
        vl[(32 + rr) * 68 + ct * 32 + bl] = acc1[r];
      }
    }
    __syncthreads();
    if (sh == 1) {
      #pragma unroll
      for (int r = 0; r < 16; ++r) {
        const int rr = (r & 3) + 8 * (r >> 2) + 4 * half;
        vl[rr * 68 + ct * 32 + bl]        += acc0[r];
        vl[(32 + rr) * 68 + ct * 32 + bl] += acc1[r];
      }
    }
    __syncthreads();
  };

  // ---------------- pass 1: v[b,k] ----------------
  run_pass(w1h);
  combine();
  // z <- v (f32 -> f16)
  #pragma unroll
  for (int u = 0; u < 2; ++u) {
    const int s = 2 * sh + u;
    const float* vp0 = &vl[bl * 68 + s * 16 + half * 8];
    const float* vp1 = &vl[(32 + bl) * 68 + s * 16 + half * 8];
    f32x4v a = *reinterpret_cast<const f32x4v*>(vp0);
    f32x4v b = *reinterpret_cast<const f32x4v*>(vp0 + 4);
    f32x4v c = *reinterpret_cast<const f32x4v*>(vp1);
    f32x4v d = *reinterpret_cast<const f32x4v*>(vp1 + 4);
    z0[u][0] = f16x2{(f16)a[0],(f16)a[1]}; z0[u][1] = f16x2{(f16)a[2],(f16)a[3]};
    z0[u][2] = f16x2{(f16)b[0],(f16)b[1]}; z0[u][3] = f16x2{(f16)b[2],(f16)b[3]};
    z1[u][0] = f16x2{(f16)c[0],(f16)c[1]}; z1[u][1] = f16x2{(f16)c[2],(f16)c[3]};
    z1[u][2] = f16x2{(f16)d[0],(f16)d[1]}; z1[u][3] = f16x2{(f16)d[2],(f16)d[3]};
  }
  __syncthreads();  // vl consumed before pass-2 staging overwrites stage[0]

  // ---------------- pass 2: out[b,e] ----------------
  run_pass(w2h);
  combine();
  for (int q = t; q < 1024; q += 256) {
    const int row = q >> 4, c4 = (q & 15) * 4;
    f32x4v v4 = *reinterpret_cast<const f32x4v*>(&vl[row * 68 + c4]);
    f32x4v o;
    o[0] = v4[0] * 0.125f; o[1] = v4[1] * 0.125f;
    o[2] = v4[2] * 0.125f; o[3] = v4[3] * 0.125f;
    *reinterpret_cast<f32x4v*>(&out[(base + row) * 64 + c4]) = o;
  }
}

extern "C" void kernel_launch(void* const* d_in, const int* in_sizes, int n_in,
                              void* d_out, int out_size, void* d_ws, size_t ws_size,
                              hipStream_t stream) {
  const float* x = (const float*)d_in[0];
  const float* g = (const float*)d_in[1];
  const float* W = (const float*)d_in[2];
  float* o = (float*)d_out;
  u16* w1h = (u16*)d_ws;                    // 65*4096 f16 = 520 KiB
  u16* w2h = w1h + 65 * 4096;               // another 520 KiB
  hipLaunchKernelGGL(prep_w, dim3(65), dim3(256), 0, stream, W, w1h, w2h);
  hipLaunchKernelGGL(rquad_main, dim3(512), dim3(256), 0, stream, x, g, w1h, w2h, o);
}